// Round 4
// baseline (1177.693 us; speedup 1.0000x reference)
//
#include <hip/hip_runtime.h>

#define DIM 512
#define NROWS 131072

typedef __attribute__((ext_vector_type(8))) __bf16 bf16x8;
typedef __attribute__((ext_vector_type(4))) float f32x4;

union BF8 { unsigned short us[8]; bf16x8 v; };

__device__ __forceinline__ unsigned short f2bf(float f) {
  unsigned u = __builtin_bit_cast(unsigned, f);
  return (unsigned short)((u + 0x7FFFu + ((u >> 16) & 1u)) >> 16);
}
__device__ __forceinline__ float bf2f(unsigned short u) {
  return __builtin_bit_cast(float, (unsigned)u << 16);
}

__device__ __forceinline__ f32x4 mfma16(bf16x8 a, bf16x8 b, f32x4 c) {
  return __builtin_amdgcn_mfma_f32_16x16x32_bf16(a, b, c, 0, 0, 0);
}

__device__ __forceinline__ float sigmoid_fast(float v) {
  return 1.0f / (1.0f + __expf(-v));
}
__device__ __forceinline__ float tanh_fast(float v) {
  float e = __expf(2.0f * v);
  return 1.0f - 2.0f / (e + 1.0f);
}

__device__ __forceinline__ void gl2lds(const unsigned char* g, unsigned char* l) {
  __builtin_amdgcn_global_load_lds(
      (const __attribute__((address_space(1))) unsigned int*)g,
      (__attribute__((address_space(3))) unsigned int*)l, 16, 0, 0);
}

// ---------------------------------------------------------------------------
// Weight pre-pack: fp32 W[out=512][in=512] -> bf16 B-fragments.
// Frag (gate g, kstep f, colfrag c): lane l holds 8 bf16 =
//   W[c*16 + (l&15)][f*32 + (l>>4)*8 + 0..7]
// elem index = ((g*16+f)*32 + c)*512 + l*8 + e.  Gate order: rx,zx,rh,zh,nx,nh.
// ---------------------------------------------------------------------------
__global__ void prepack_weights(const float* __restrict__ W0, const float* __restrict__ W1,
                                const float* __restrict__ W2, const float* __restrict__ W3,
                                const float* __restrict__ W4, const float* __restrict__ W5,
                                unsigned short* __restrict__ out) {
  int idx = blockIdx.x * 256 + threadIdx.x;
  int e = idx & 7;
  int l = (idx >> 3) & 63;
  int c = (idx >> 9) & 31;
  int f = (idx >> 14) & 15;
  int g = idx >> 18;
  const float* W = (g == 0) ? W0 : (g == 1) ? W1 : (g == 2) ? W2
                 : (g == 3) ? W3 : (g == 4) ? W4 : W5;
  int row = c * 16 + (l & 15);
  int kk  = f * 32 + ((l >> 4) << 3) + e;
  out[idx] = f2bf(W[row * DIM + kk]);
}

// ===========================================================================
// Split path: two m97-style 128x128-tile GEMMs, 256 thr / 4 waves, 48KB LDS,
// 3 blocks/CU.  B frag-packed (conflict-free); A fp32 / rh bf16 staged with
// source-side XOR swizzle (linear gl2lds dest, <=2-way bank aliasing).
// ===========================================================================

// G1: C[N x 1024] = [x|h] @ [Wrx|Wrh ; Wzx|Wzh]^T.
//   col tiles n=0..3 -> r (gates 0/2), n=4..7 -> z (gates 1/3).
//   r-epilogue: rh = sigmoid(.)*h -> rhws (bf16). z-epilogue: sigmoid -> zout.
__global__ __launch_bounds__(256, 3)
void gemm_rz(const float* __restrict__ x, const float* __restrict__ h,
             const unsigned char* __restrict__ WB,
             const float* __restrict__ b_rx, const float* __restrict__ b_rh,
             const float* __restrict__ b_zx, const float* __restrict__ b_zh,
             unsigned short* __restrict__ rhws, float* __restrict__ zout) {
  __shared__ __align__(1024) unsigned char ldsA[2][16384];
  __shared__ __align__(1024) unsigned char ldsB[2][8192];

  const int tid = threadIdx.x;
  const int lane = tid & 63;
  const int w = tid >> 6;              // 0..3
  const int lr = lane & 15, lk = lane >> 4;
  const int row0w = (w & 1) * 64;      // wave rows within 128
  const int cfw = (w >> 1) * 4;        // wave col-frag base within 8

  // XCD-bijective swizzle: 8192 blocks -> 1024 consecutive per XCD
  const int bid = blockIdx.x;
  const int swz = (bid & 7) * 1024 + (bid >> 3);
  const int panel = swz >> 3;          // 0..1023 (128-row panel)
  const int n = swz & 7;               // col tile
  const int row0 = panel * 128;
  const bool isR = (n < 4);
  const int gx = isR ? 0 : 1, gh = isR ? 2 : 3;
  const int c0 = (n & 3) * 8;          // first col-frag of this tile in gate

  f32x4 acc[4][4] = {};

  auto stageA = [&](int f, int buf) {  // 16KB fp32: rows row0..+128, k fk*32..+32
    const float* src = (f < 16) ? x : h;
    const int fk = f & 15;
#pragma unroll
    for (int it = 0; it < 4; ++it) {
      int d = it * 4096 + tid * 16;
      int row = d >> 7;                // d/128
      int u = (d >> 4) & 7;            // 16B unit within 128B row
      const unsigned char* s =
          (const unsigned char*)(src + (size_t)(row0 + row) * DIM + fk * 32)
          + (((u ^ (row & 7)) & 7) << 4);
      gl2lds(s, &ldsA[buf][d]);
    }
  };
  auto stageB = [&](int g, int fk, int buf) {  // 8KB = 8 col-frags
    const unsigned char* s = WB + ((size_t)((g * 16 + fk) * 32 + c0) << 10);
#pragma unroll
    for (int it = 0; it < 2; ++it) {
      int d = it * 4096 + tid * 16;
      gl2lds(s + d, &ldsB[buf][d]);
    }
  };
  auto compute = [&](int buf) {
    bf16x8 bfr[4], af[4];
#pragma unroll
    for (int cf = 0; cf < 4; ++cf)
      bfr[cf] = *(const bf16x8*)&ldsB[buf][(cfw + cf) * 1024 + lane * 16];
#pragma unroll
    for (int rf = 0; rf < 4; ++rf) {
      int rfr = row0w + rf * 16 + lr;
      int u0 = lk * 2;
      f32x4 a0 = *(const f32x4*)&ldsA[buf][rfr * 128 + (((u0) ^ (rfr & 7)) << 4)];
      f32x4 a1 = *(const f32x4*)&ldsA[buf][rfr * 128 + (((u0 + 1) ^ (rfr & 7)) << 4)];
      union { __bf16 e[8]; bf16x8 v; } cv;
      cv.e[0] = (__bf16)a0[0]; cv.e[1] = (__bf16)a0[1];
      cv.e[2] = (__bf16)a0[2]; cv.e[3] = (__bf16)a0[3];
      cv.e[4] = (__bf16)a1[0]; cv.e[5] = (__bf16)a1[1];
      cv.e[6] = (__bf16)a1[2]; cv.e[7] = (__bf16)a1[3];
      af[rf] = cv.v;
    }
#pragma unroll
    for (int rf = 0; rf < 4; ++rf)
#pragma unroll
      for (int cf = 0; cf < 4; ++cf)
        acc[rf][cf] = mfma16(af[rf], bfr[cf], acc[rf][cf]);
  };

  stageA(0, 0); stageB(gx, 0, 0);
  __syncthreads();
#pragma unroll 1
  for (int f = 0; f < 32; ++f) {
    int buf = f & 1;
    if (f < 31) {
      int fn = f + 1;
      stageA(fn, buf ^ 1);
      stageB((fn < 16) ? gx : gh, fn & 15, buf ^ 1);
    }
    compute(buf);
    __syncthreads();
  }

  // epilogue
  const float* bx = isR ? b_rx : b_zx;
  const float* bh = isR ? b_rh : b_zh;
  const int coltile = (n & 3) * 128;   // column base within the gate (0..511)
#pragma unroll
  for (int cf = 0; cf < 4; ++cf) {
    int cg = coltile + (cfw + cf) * 16 + lr;
    float bsum = bx[cg] + bh[cg];
#pragma unroll
    for (int rf = 0; rf < 4; ++rf) {
#pragma unroll
      for (int j = 0; j < 4; ++j) {
        int row = row0 + row0w + rf * 16 + lk * 4 + j;
        size_t off = (size_t)row * DIM + cg;
        float v = acc[rf][cf][j] + bsum;
        if (isR) {
          float rv = sigmoid_fast(v);
          rhws[off] = f2bf(rv * h[off]);
        } else {
          zout[off] = sigmoid_fast(v);
        }
      }
    }
  }
}

// G2: C[N x 512] = [x|rh] @ [Wnx|Wnh]^T; epilogue reads z (in `out`), h; writes out.
__global__ __launch_bounds__(256, 3)
void gemm_n(const float* __restrict__ x, const float* __restrict__ h,
            const unsigned char* __restrict__ WB,
            const unsigned short* __restrict__ rhws,
            const float* __restrict__ b_nx, const float* __restrict__ b_nh,
            float* __restrict__ out) {
  __shared__ __align__(1024) unsigned char ldsA[2][16384];
  __shared__ __align__(1024) unsigned char ldsB[2][8192];

  const int tid = threadIdx.x;
  const int lane = tid & 63;
  const int w = tid >> 6;
  const int lr = lane & 15, lk = lane >> 4;
  const int row0w = (w & 1) * 64;
  const int cfw = (w >> 1) * 4;

  const int bid = blockIdx.x;            // 4096 blocks
  const int swz = (bid & 7) * 512 + (bid >> 3);
  const int panel = swz >> 2;
  const int n = swz & 3;
  const int row0 = panel * 128;
  const int c0 = n * 8;

  f32x4 acc[4][4] = {};

  auto stageA = [&](int fk, int buf) {   // fp32 x slice, 16KB
#pragma unroll
    for (int it = 0; it < 4; ++it) {
      int d = it * 4096 + tid * 16;
      int row = d >> 7;
      int u = (d >> 4) & 7;
      const unsigned char* s =
          (const unsigned char*)(x + (size_t)(row0 + row) * DIM + fk * 32)
          + (((u ^ (row & 7)) & 7) << 4);
      gl2lds(s, &ldsA[buf][d]);
    }
  };
  auto stageRH = [&](int f2, int buf) {  // bf16 rh slice, 8KB (64B/row)
    const unsigned char* base = (const unsigned char*)rhws;
#pragma unroll
    for (int it = 0; it < 2; ++it) {
      int d = it * 4096 + tid * 16;
      int row = d >> 6;                  // d/64
      int u = (d >> 4) & 3;
      const unsigned char* s = base + (size_t)(row0 + row) * 1024 + f2 * 64
                               + ((u ^ ((row >> 1) & 3)) << 4);
      gl2lds(s, &ldsA[buf][d]);
    }
  };
  auto stageB = [&](int g, int fk, int buf) {
    const unsigned char* s = WB + ((size_t)((g * 16 + fk) * 32 + c0) << 10);
#pragma unroll
    for (int it = 0; it < 2; ++it) {
      int d = it * 4096 + tid * 16;
      gl2lds(s + d, &ldsB[buf][d]);
    }
  };
  auto loadB = [&](int buf, bf16x8 (&bfr)[4]) {
#pragma unroll
    for (int cf = 0; cf < 4; ++cf)
      bfr[cf] = *(const bf16x8*)&ldsB[buf][(cfw + cf) * 1024 + lane * 16];
  };
  auto domfma = [&](bf16x8 (&af)[4], bf16x8 (&bfr)[4]) {
#pragma unroll
    for (int rf = 0; rf < 4; ++rf)
#pragma unroll
      for (int cf = 0; cf < 4; ++cf)
        acc[rf][cf] = mfma16(af[rf], bfr[cf], acc[rf][cf]);
  };
  auto computeX = [&](int buf) {
    bf16x8 bfr[4], af[4];
    loadB(buf, bfr);
#pragma unroll
    for (int rf = 0; rf < 4; ++rf) {
      int rfr = row0w + rf * 16 + lr;
      int u0 = lk * 2;
      f32x4 a0 = *(const f32x4*)&ldsA[buf][rfr * 128 + (((u0) ^ (rfr & 7)) << 4)];
      f32x4 a1 = *(const f32x4*)&ldsA[buf][rfr * 128 + (((u0 + 1) ^ (rfr & 7)) << 4)];
      union { __bf16 e[8]; bf16x8 v; } cv;
      cv.e[0] = (__bf16)a0[0]; cv.e[1] = (__bf16)a0[1];
      cv.e[2] = (__bf16)a0[2]; cv.e[3] = (__bf16)a0[3];
      cv.e[4] = (__bf16)a1[0]; cv.e[5] = (__bf16)a1[1];
      cv.e[6] = (__bf16)a1[2]; cv.e[7] = (__bf16)a1[3];
      af[rf] = cv.v;
    }
    domfma(af, bfr);
  };
  auto computeRH = [&](int buf) {
    bf16x8 bfr[4], af[4];
    loadB(buf, bfr);
#pragma unroll
    for (int rf = 0; rf < 4; ++rf) {
      int rfr = row0w + rf * 16 + lr;
      af[rf] = *(const bf16x8*)&ldsA[buf][rfr * 64 + ((lk ^ ((rfr >> 1) & 3)) << 4)];
    }
    domfma(af, bfr);
  };

  stageA(0, 0); stageB(4, 0, 0);
  __syncthreads();
#pragma unroll 1
  for (int f = 0; f < 32; ++f) {
    int buf = f & 1;
    if (f < 31) {
      int fn = f + 1;
      if (fn < 16) { stageA(fn, buf ^ 1);      stageB(4, fn, buf ^ 1); }
      else         { stageRH(fn - 16, buf ^ 1); stageB(5, fn - 16, buf ^ 1); }
    }
    if (f < 16) computeX(buf); else computeRH(buf);
    __syncthreads();
  }

  // epilogue: n = tanh(acc + b); out = (1-z)*n + z*h  (z was staged in `out`)
#pragma unroll
  for (int cf = 0; cf < 4; ++cf) {
    int cg = n * 128 + (cfw + cf) * 16 + lr;
    float bsum = b_nx[cg] + b_nh[cg];
#pragma unroll
    for (int rf = 0; rf < 4; ++rf) {
#pragma unroll
      for (int j = 0; j < 4; ++j) {
        int row = row0 + row0w + rf * 16 + lk * 4 + j;
        size_t off = (size_t)row * DIM + cg;
        float nv = tanh_fast(acc[rf][cf][j] + bsum);
        float zv = out[off];
        out[off] = (1.0f - zv) * nv + zv * h[off];
      }
    }
  }
}

// ===========================================================================
// Fallback (round-3 fused kernel) if ws_size is too small for the rh buffer.
// ===========================================================================
#define RH_OFF 65536
#define X_OFF  131072
#define LDS_BYTES 139264

__global__ __launch_bounds__(512, 1)
void gru_fused(const float* __restrict__ x, const float* __restrict__ h,
               const unsigned char* __restrict__ WB,
               const float* __restrict__ b_rx, const float* __restrict__ b_rh,
               const float* __restrict__ b_zx, const float* __restrict__ b_zh,
               const float* __restrict__ b_nx, const float* __restrict__ b_nh,
               float* __restrict__ out) {
  __shared__ __align__(1024) unsigned char lds[LDS_BYTES];

  const int tid  = threadIdx.x;
  const int lane = tid & 63;
  const int w    = tid >> 6;
  const int cfg0 = w * 4;
  const int row0 = blockIdx.x * 64;
  const int lr   = lane & 15;
  const int lk   = lane >> 4;

  auto stageChunk = [&](int g, int f, int dstOff) {
    const unsigned char* src = WB + (size_t)(g * 16 + f) * 32768;
#pragma unroll
    for (int it = 0; it < 4; ++it) {
      int o = (it * 512 + tid) * 16;
      gl2lds(src + o, &lds[dstOff + o]);
    }
  };

  float4 xreg;
  auto loadX = [&](int f) {
    int row = tid >> 3, kq = tid & 7;
    xreg = *(const float4*)(x + (size_t)(row0 + row) * DIM + f * 32 + kq * 4);
  };
  auto writeX = [&](int f) {
    int row = tid >> 3, kq = tid & 7;
    union { unsigned short us[4]; uint2 v; } p;
    p.us[0] = f2bf(xreg.x); p.us[1] = f2bf(xreg.y);
    p.us[2] = f2bf(xreg.z); p.us[3] = f2bf(xreg.w);
    *(uint2*)&lds[X_OFF + (f & 1) * 4096 + (row >> 4) * 1024
                  + ((kq >> 1) * 16 + (row & 15)) * 16 + (kq & 1) * 8] = p.v;
  };

  auto gateStage = [&](int abase, int bbase, f32x4 (&A)[4][4]) {
    bf16x8 af[4], bfr[4];
#pragma unroll
    for (int rf = 0; rf < 4; ++rf)
      af[rf] = *(const bf16x8*)&lds[abase + rf * 1024 + lane * 16];
#pragma unroll
    for (int cf = 0; cf < 4; ++cf)
      bfr[cf] = *(const bf16x8*)&lds[bbase + (cfg0 + cf) * 1024 + lane * 16];
#pragma unroll
    for (int rf = 0; rf < 4; ++rf)
#pragma unroll
      for (int cf = 0; cf < 4; ++cf)
        A[rf][cf] = mfma16(af[rf], bfr[cf], A[rf][cf]);
  };

  f32x4 accR[4][4] = {}, accZ[4][4] = {};

#pragma unroll
  for (int it = 0; it < 16; ++it) {
    int i = tid + it * 512;
    int row = i >> 7, kf4 = i & 127;
    int k = kf4 * 4;
    float4 hv4 = *(const float4*)(h + (size_t)(row0 + row) * DIM + k);
    union { unsigned short us[4]; uint2 v; } p;
    p.us[0] = f2bf(hv4.x); p.us[1] = f2bf(hv4.y);
    p.us[2] = f2bf(hv4.z); p.us[3] = f2bf(hv4.w);
    *(uint2*)&lds[(k >> 5) * 4096 + (row >> 4) * 1024
                  + (((k >> 3) & 3) * 16 + (row & 15)) * 16 + (k & 4) * 2] = p.v;
  }
  loadX(0); writeX(0);
  stageChunk(0, 0, RH_OFF);
  __syncthreads();

#pragma unroll 1
  for (int f = 0; f < 16; ++f) {
    const int xoff = X_OFF + (f & 1) * 4096;
    const int hoff = f * 4096;
    stageChunk(1, f, RH_OFF + 32768);
    if (f < 15) loadX(f + 1);
    gateStage(xoff, RH_OFF, accR);
    __syncthreads();
    stageChunk(2, f, RH_OFF);
    gateStage(xoff, RH_OFF + 32768, accZ);
    __syncthreads();
    stageChunk(3, f, RH_OFF + 32768);
    if (f < 15) writeX(f + 1);
    gateStage(hoff, RH_OFF, accR);
    __syncthreads();
    if (f < 15) stageChunk(0, f + 1, RH_OFF);
    gateStage(hoff, RH_OFF + 32768, accZ);
    __syncthreads();
  }

#pragma unroll
  for (int cf = 0; cf < 4; ++cf) {
    const int col  = (cfg0 + cf) * 16 + lr;
    const float bs = b_rx[col] + b_rh[col];
    const int fcol  = col >> 5;
    const int l2b   = ((col >> 3) & 3) * 16;
    const int ebyte = (col & 7) * 2;
#pragma unroll
    for (int rf = 0; rf < 4; ++rf) {
#pragma unroll
      for (int j = 0; j < 4; ++j) {
        const int rsub = lk * 4 + j;
        unsigned short hu = *(const unsigned short*)
            &lds[fcol * 4096 + rf * 1024 + (l2b + rsub) * 16 + ebyte];
        float rv = sigmoid_fast(accR[rf][cf][j] + bs);
        *(unsigned short*)
            &lds[RH_OFF + fcol * 4096 + rf * 1024 + (l2b + rsub) * 16 + ebyte]
            = f2bf(rv * bf2f(hu));
      }
    }
  }
  __syncthreads();

  f32x4 accN[4][4] = {};
  loadX(0); writeX(0);
  stageChunk(4, 0, 0);
  __syncthreads();
#pragma unroll 1
  for (int f = 0; f < 16; ++f) {
    const int xoff = X_OFF + (f & 1) * 4096;
    stageChunk(5, f, 32768);
    if (f < 15) loadX(f + 1);
    gateStage(xoff, 0, accN);
    __syncthreads();
    if (f < 15) { stageChunk(4, f + 1, 0); writeX(f + 1); }
    gateStage(RH_OFF + f * 4096, 32768, accN);
    __syncthreads();
  }

#pragma unroll
  for (int cf = 0; cf < 4; ++cf) {
    const int col  = (cfg0 + cf) * 16 + lr;
    const float bn = b_nx[col] + b_nh[col];
    const float bz = b_zx[col] + b_zh[col];
#pragma unroll
    for (int rf = 0; rf < 4; ++rf) {
#pragma unroll
      for (int j = 0; j < 4; ++j) {
        const int row = rf * 16 + lk * 4 + j;
        const size_t off = (size_t)(row0 + row) * DIM + col;
        float hv = h[off];
        float nv = tanh_fast(accN[rf][cf][j] + bn);
        float zv = sigmoid_fast(accZ[rf][cf][j] + bz);
        out[off] = (1.0f - zv) * nv + zv * hv;
      }
    }
  }
}

extern "C" void kernel_launch(void* const* d_in, const int* in_sizes, int n_in,
                              void* d_out, int out_size, void* d_ws, size_t ws_size,
                              hipStream_t stream) {
  const float* x    = (const float*)d_in[0];
  const float* h    = (const float*)d_in[1];
  const float* W_rx = (const float*)d_in[2];
  const float* b_rx = (const float*)d_in[3];
  const float* W_rh = (const float*)d_in[4];
  const float* b_rh = (const float*)d_in[5];
  const float* W_zx = (const float*)d_in[6];
  const float* b_zx = (const float*)d_in[7];
  const float* W_zh = (const float*)d_in[8];
  const float* b_zh = (const float*)d_in[9];
  const float* W_nx = (const float*)d_in[10];
  const float* b_nx = (const float*)d_in[11];
  const float* W_nh = (const float*)d_in[12];
  const float* b_nh = (const float*)d_in[13];

  unsigned char* ws = (unsigned char*)d_ws;
  unsigned short* wpack = (unsigned short*)ws;   // 3 MiB

  // gate order: rx, zx, rh, zh, nx, nh
  prepack_weights<<<6144, 256, 0, stream>>>(W_rx, W_zx, W_rh, W_zh, W_nx, W_nh, wpack);

  const size_t need = (4ull << 20) + (size_t)NROWS * DIM * 2;  // wpack + rh bf16
  if (ws_size >= need) {
    unsigned short* rhws = (unsigned short*)(ws + (4ull << 20));
    gemm_rz<<<8192, 256, 0, stream>>>(x, h, (const unsigned char*)wpack,
                                      b_rx, b_rh, b_zx, b_zh,
                                      rhws, (float*)d_out);
    gemm_n<<<4096, 256, 0, stream>>>(x, h, (const unsigned char*)wpack,
                                     rhws, b_nx, b_nh, (float*)d_out);
  } else {
    gru_fused<<<NROWS / 64, 512, 0, stream>>>(x, h, (const unsigned char*)wpack,
                                              b_rx, b_rh, b_zx, b_zh, b_nx, b_nh,
                                              (float*)d_out);
  }
}

// Round 5
// 671.085 us; speedup vs baseline: 1.7549x; 1.7549x over previous
//
#include <hip/hip_runtime.h>

#define DIM 512
#define NROWS 131072

typedef __attribute__((ext_vector_type(8))) __bf16 bf16x8;
typedef __attribute__((ext_vector_type(4))) float f32x4;

__device__ __forceinline__ unsigned short f2bf(float f) {
  unsigned u = __builtin_bit_cast(unsigned, f);
  return (unsigned short)((u + 0x7FFFu + ((u >> 16) & 1u)) >> 16);
}
__device__ __forceinline__ float bf2f(unsigned short u) {
  return __builtin_bit_cast(float, (unsigned)u << 16);
}

__device__ __forceinline__ f32x4 mfma16(bf16x8 a, bf16x8 b, f32x4 c) {
  return __builtin_amdgcn_mfma_f32_16x16x32_bf16(a, b, c, 0, 0, 0);
}

__device__ __forceinline__ float sigmoid_fast(float v) {
  return 1.0f / (1.0f + __expf(-v));
}
__device__ __forceinline__ float tanh_fast(float v) {
  float e = __expf(2.0f * v);
  return 1.0f - 2.0f / (e + 1.0f);
}

__device__ __forceinline__ void gl2lds(const void* g, void* l) {
  __builtin_amdgcn_global_load_lds(
      (const __attribute__((address_space(1))) unsigned int*)g,
      (__attribute__((address_space(3))) unsigned int*)l, 16, 0, 0);
}

// ---------------------------------------------------------------------------
// Weight pre-pack: fp32 W[out=512][in=512] -> bf16 B-fragments.
// Frag (gate g, kstep f, colfrag c): lane l holds 8 bf16 =
//   W[c*16 + (l&15)][f*32 + (l>>4)*8 + 0..7]
// elem index = ((g*16+f)*32 + c)*512 + l*8 + e.  Gates: rx,zx,rh,zh,nx,nh.
// ---------------------------------------------------------------------------
__global__ void prepack_weights(const float* __restrict__ W0, const float* __restrict__ W1,
                                const float* __restrict__ W2, const float* __restrict__ W3,
                                const float* __restrict__ W4, const float* __restrict__ W5,
                                unsigned short* __restrict__ out) {
  int idx = blockIdx.x * 256 + threadIdx.x;
  int e = idx & 7;
  int l = (idx >> 3) & 63;
  int c = (idx >> 9) & 31;
  int f = (idx >> 14) & 15;
  int g = idx >> 18;
  const float* W = (g == 0) ? W0 : (g == 1) ? W1 : (g == 2) ? W2
                 : (g == 3) ? W3 : (g == 4) ? W4 : W5;
  int row = c * 16 + (l & 15);
  int kk  = f * 32 + ((l >> 4) << 3) + e;
  out[idx] = f2bf(W[row * DIM + kk]);
}

// x -> bf16 row-major (for async gl2lds A-staging in the main kernel)
__global__ void prep_x(const float* __restrict__ x, unsigned short* __restrict__ xb) {
  size_t i = (size_t)(blockIdx.x * 256 + threadIdx.x) * 8;
  float4 a0 = *(const float4*)(x + i);
  float4 a1 = *(const float4*)(x + i + 4);
  union { unsigned short us[8]; uint4 v; } p;
  p.us[0] = f2bf(a0.x); p.us[1] = f2bf(a0.y); p.us[2] = f2bf(a0.z); p.us[3] = f2bf(a0.w);
  p.us[4] = f2bf(a1.x); p.us[5] = f2bf(a1.y); p.us[6] = f2bf(a1.z); p.us[7] = f2bf(a1.w);
  *(uint4*)(xb + i) = p.v;
}

// LDS map (bytes):
//   [0, 64K)       sweep1: h frags [f16][rf4][lane][16B]; sweep2: B dbuf 2x32K
//   [64K, 128K)    sweep1: B dbuf 2x32K; after r-epilogue: rh frags
//   [128K, 144K)   x dbuf 2x8K  [pair][fh2][rf4][lane][16B]
#define BOFF 65536
#define XOFF 131072
#define LDS_BYTES 147456

// ---------------------------------------------------------------------------
// Fused GRU, counted-vmcnt schedule (T3 min + T4). Block = 64r x 512c,
// 8 waves, wave = 64r x 64c.  Window = {issue stage; vmcnt(N); s_barrier;
// ds_read + 16 MFMA; s_barrier} — loads stay in flight across barriers.
// ---------------------------------------------------------------------------
__global__ __launch_bounds__(512, 1)
void gru_fused(const float* __restrict__ x, const float* __restrict__ h,
               const unsigned short* __restrict__ xb,
               const unsigned char* __restrict__ WB,
               const float* __restrict__ b_rx, const float* __restrict__ b_rh,
               const float* __restrict__ b_zx, const float* __restrict__ b_zh,
               const float* __restrict__ b_nx, const float* __restrict__ b_nh,
               float* __restrict__ out) {
  __shared__ __align__(1024) unsigned char lds[LDS_BYTES];

  const int tid  = threadIdx.x;
  const int lane = tid & 63;
  const int w    = tid >> 6;
  const int cfg0 = w * 4;
  const int row0 = blockIdx.x * 64;
  const int lr   = lane & 15;
  const int lk   = lane >> 4;

  auto stageB = [&](int g, int f, int dst) {   // 32KB chunk, 4 gl2lds/thread
    const unsigned char* src = WB + (size_t)(g * 16 + f) * 32768;
#pragma unroll
    for (int it = 0; it < 4; ++it) {
      int o = (it * 512 + tid) * 16;
      gl2lds(src + o, &lds[dst + o]);
    }
  };
  auto stageXpair = [&](int p) {               // 8KB: k = p*64..+64, 1 gl2lds
    int fh = tid >> 8, rf = (tid >> 6) & 3, l = tid & 63;
    const unsigned short* src = xb + (size_t)(row0 + rf * 16 + (l & 15)) * DIM
                                + p * 64 + fh * 32 + (l >> 4) * 8;
    gl2lds(src, &lds[XOFF + (p & 1) * 8192 + tid * 16]);
  };
  auto gateStage = [&](int abase, int bbase, f32x4 (&A)[4][4]) {
    bf16x8 af[4], bfr[4];
#pragma unroll
    for (int rf = 0; rf < 4; ++rf)
      af[rf] = *(const bf16x8*)&lds[abase + rf * 1024 + lane * 16];
#pragma unroll
    for (int cf = 0; cf < 4; ++cf)
      bfr[cf] = *(const bf16x8*)&lds[bbase + (cfg0 + cf) * 1024 + lane * 16];
#pragma unroll
    for (int rf = 0; rf < 4; ++rf)
#pragma unroll
      for (int cf = 0; cf < 4; ++cf)
        A[rf][cf] = mfma16(af[rf], bfr[cf], A[rf][cf]);
  };

  f32x4 accR[4][4] = {}, accZ[4][4] = {};

  // ---- prologue: h (fp32->bf16 frags, one-time), x pair0, rx0 ----
#pragma unroll
  for (int it = 0; it < 16; ++it) {
    int i = tid + it * 512;
    int row = i >> 7;
    int k = (i & 127) * 4;
    float4 hv4 = *(const float4*)(h + (size_t)(row0 + row) * DIM + k);
    union { unsigned short us[4]; uint2 v; } p;
    p.us[0] = f2bf(hv4.x); p.us[1] = f2bf(hv4.y);
    p.us[2] = f2bf(hv4.z); p.us[3] = f2bf(hv4.w);
    *(uint2*)&lds[(k >> 5) * 4096 + (row >> 4) * 1024
                  + (((k >> 3) & 3) * 16 + (row & 15)) * 16 + (k & 4) * 2] = p.v;
  }
  stageXpair(0);
  stageB(0, 0, BOFF);                 // rx0 -> b0
  __syncthreads();                    // one full drain; pipeline starts clean

  // ---- sweep 1: f x {rx, zx, rh, zh}; counted vmcnt, raw barriers ----
#pragma unroll 1
  for (int f = 0; f < 16; ++f) {
    const int xo = XOFF + ((f >> 1) & 1) * 8192 + (f & 1) * 4096;
    const int ho = f * 4096;
    // W0: compute rx(f)@b0; stage zx(f)->b1 (+ x pair on odd f)
    stageB(1, f, BOFF + 32768);
    if (f & 1) {
      int p1 = (f >> 1) + 1; if (p1 > 7) p1 = 7;
      stageXpair(p1);
      asm volatile("s_waitcnt vmcnt(5)" ::: "memory");
    } else {
      asm volatile("s_waitcnt vmcnt(4)" ::: "memory");
    }
    __builtin_amdgcn_s_barrier();
    gateStage(xo, BOFF, accR);
    __builtin_amdgcn_s_barrier();
    // W1: compute zx(f)@b1; stage rh(f)->b0
    stageB(2, f, BOFF);
    asm volatile("s_waitcnt vmcnt(4)" ::: "memory");
    __builtin_amdgcn_s_barrier();
    gateStage(xo, BOFF + 32768, accZ);
    __builtin_amdgcn_s_barrier();
    // W2: compute rh(f)@b0; stage zh(f)->b1
    stageB(3, f, BOFF + 32768);
    asm volatile("s_waitcnt vmcnt(4)" ::: "memory");
    __builtin_amdgcn_s_barrier();
    gateStage(ho, BOFF, accR);
    __builtin_amdgcn_s_barrier();
    // W3: compute zh(f)@b1; stage rx(f+1)->b0
    if (f < 15) {
      stageB(0, f + 1, BOFF);
      asm volatile("s_waitcnt vmcnt(4)" ::: "memory");
    } else {
      asm volatile("s_waitcnt vmcnt(0)" ::: "memory");
    }
    __builtin_amdgcn_s_barrier();
    gateStage(ho, BOFF + 32768, accZ);
    __builtin_amdgcn_s_barrier();
  }

  // ---- r-epilogue: r = sigmoid(accR+b); rh = r*h -> frag LDS @BOFF ----
#pragma unroll
  for (int cf = 0; cf < 4; ++cf) {
    const int col  = (cfg0 + cf) * 16 + lr;
    const float bs = b_rx[col] + b_rh[col];
    const int fcol  = col >> 5;
    const int l2b   = ((col >> 3) & 3) * 16;
    const int ebyte = (col & 7) * 2;
#pragma unroll
    for (int rf = 0; rf < 4; ++rf) {
#pragma unroll
      for (int j = 0; j < 4; ++j) {
        const int rsub = lk * 4 + j;
        unsigned short hu = *(const unsigned short*)
            &lds[fcol * 4096 + rf * 1024 + (l2b + rsub) * 16 + ebyte];
        float rv = sigmoid_fast(accR[rf][cf][j] + bs);
        *(unsigned short*)
            &lds[BOFF + fcol * 4096 + rf * 1024 + (l2b + rsub) * 16 + ebyte]
            = f2bf(rv * bf2f(hu));
      }
    }
  }
  __syncthreads();                    // rh visible; h region now dead

  // ---- sweep 2: f x {nx, nh}; B dbuf @0; A(nh) = rh frags @BOFF ----
  f32x4 accN[4][4] = {};
  stageXpair(0);
  stageB(4, 0, 0);                    // nx0 -> b0@0 (5 loads in flight)
#pragma unroll 1
  for (int f = 0; f < 16; ++f) {
    const int xo = XOFF + ((f >> 1) & 1) * 8192 + (f & 1) * 4096;
    // W0: compute nx(f)@b0; stage nh(f)->b1 (+ x pair on odd f)
    stageB(5, f, 32768);
    if (f & 1) {
      int p1 = (f >> 1) + 1; if (p1 > 7) p1 = 7;
      stageXpair(p1);
      asm volatile("s_waitcnt vmcnt(5)" ::: "memory");
    } else {
      asm volatile("s_waitcnt vmcnt(4)" ::: "memory");
    }
    __builtin_amdgcn_s_barrier();
    gateStage(xo, 0, accN);
    __builtin_amdgcn_s_barrier();
    // W1: compute nh(f)@b1; stage nx(f+1)->b0
    if (f < 15) {
      stageB(4, f + 1, 0);
      asm volatile("s_waitcnt vmcnt(4)" ::: "memory");
    } else {
      asm volatile("s_waitcnt vmcnt(0)" ::: "memory");
    }
    __builtin_amdgcn_s_barrier();
    gateStage(BOFF + f * 4096, 32768, accN);
    __builtin_amdgcn_s_barrier();
  }

  // ---- final epilogue: n = tanh(accN+b), z = sigmoid(accZ+b), combine ----
#pragma unroll
  for (int cf = 0; cf < 4; ++cf) {
    const int col  = (cfg0 + cf) * 16 + lr;
    const float bn = b_nx[col] + b_nh[col];
    const float bz = b_zx[col] + b_zh[col];
#pragma unroll
    for (int rf = 0; rf < 4; ++rf) {
#pragma unroll
      for (int j = 0; j < 4; ++j) {
        const int row = rf * 16 + lk * 4 + j;
        const size_t off = (size_t)(row0 + row) * DIM + col;
        float hv = h[off];
        float nv = tanh_fast(accN[rf][cf][j] + bn);
        float zv = sigmoid_fast(accZ[rf][cf][j] + bz);
        out[off] = (1.0f - zv) * nv + zv * hv;
      }
    }
  }
}

extern "C" void kernel_launch(void* const* d_in, const int* in_sizes, int n_in,
                              void* d_out, int out_size, void* d_ws, size_t ws_size,
                              hipStream_t stream) {
  const float* x    = (const float*)d_in[0];
  const float* h    = (const float*)d_in[1];
  const float* W_rx = (const float*)d_in[2];
  const float* b_rx = (const float*)d_in[3];
  const float* W_rh = (const float*)d_in[4];
  const float* b_rh = (const float*)d_in[5];
  const float* W_zx = (const float*)d_in[6];
  const float* b_zx = (const float*)d_in[7];
  const float* W_zh = (const float*)d_in[8];
  const float* b_zh = (const float*)d_in[9];
  const float* W_nx = (const float*)d_in[10];
  const float* b_nx = (const float*)d_in[11];
  const float* W_nh = (const float*)d_in[12];
  const float* b_nh = (const float*)d_in[13];

  unsigned char* ws = (unsigned char*)d_ws;
  unsigned short* wpack = (unsigned short*)ws;                 // 3 MiB
  unsigned short* xb    = (unsigned short*)(ws + (4ull << 20)); // 128 MiB bf16 x

  // gate order: rx, zx, rh, zh, nx, nh
  prepack_weights<<<6144, 256, 0, stream>>>(W_rx, W_zx, W_rh, W_zh, W_nx, W_nh, wpack);
  prep_x<<<32768, 256, 0, stream>>>(x, xb);
  gru_fused<<<NROWS / 64, 512, 0, stream>>>(x, h, xb, (const unsigned char*)wpack,
                                            b_rx, b_rh, b_zx, b_zh, b_nx, b_nh,
                                            (float*)d_out);
}